// Round 10
// baseline (293.740 us; speedup 1.0000x reference)
//
#include <hip/hip_runtime.h>
#include <math.h>

typedef unsigned short u16;
typedef __attribute__((ext_vector_type(8))) short    bf16x8;
typedef __attribute__((ext_vector_type(8))) unsigned short u16x8;
typedef __attribute__((ext_vector_type(4))) float    f32x4;

// Problem constants
#define NB   32        // batch
#define NC   256       // in channels
#define NO   256       // out channels
#define NH   56
#define NW   56
#define NP   3136      // H*W
#define NE   8
#define NID  64
#define HP   58        // padded rows
#define WP   64        // padded row width (aligned)

// Workspace layout (bytes)
#define WMIX_OFF   0                    // u16 [32][9][256][256] = 37,748,736 B
#define XPT_OFF    37748736             // u16 [32][58][64][256] = 60,817,408 B
#define POOL_OFF   98566144             // f32 [32][256]
#define RBUF_OFF   98598912             // f32 [32][8]

__device__ __forceinline__ u16 f2bf(float f) {
    unsigned u = __float_as_uint(f);
    unsigned r = (u + 0x7FFFu + ((u >> 16) & 1u)) >> 16;   // RNE
    return (u16)r;
}

__device__ __forceinline__ void gl_lds16(const void* g, void* l) {
    __builtin_amdgcn_global_load_lds(
        (const __attribute__((address_space(1))) unsigned int*)g,
        (__attribute__((address_space(3))) unsigned int*)l, 16, 0, 0);
}

#define SBAR() __builtin_amdgcn_sched_barrier(0);
// counted wait (perf hint only; correctness is register-dep guaranteed)
#define VM_WAIT(N) { asm volatile("s_waitcnt vmcnt(" #N ")" ::: "memory"); \
                     __builtin_amdgcn_sched_barrier(0); }

// ---------------------------------------------------------------- kernel 0
// Zero pooled accumulators + the two border rows (h'=0,57) of xpadT.
__global__ __launch_bounds__(256) void zero_k(float* __restrict__ pooled,
                                              u16* __restrict__ xpadT) {
    int b = blockIdx.x, t = threadIdx.x;
    pooled[b * 256 + t] = 0.0f;
    u16x8 z = {0, 0, 0, 0, 0, 0, 0, 0};
    u16* r0 = xpadT + ((size_t)(b * HP + 0)) * WP * NC;
    u16* r1 = xpadT + ((size_t)(b * HP + 57)) * WP * NC;
    #pragma unroll
    for (int i = 0; i < 8; ++i) {
        *(u16x8*)&r0[(i * 256 + t) * 8] = z;
        *(u16x8*)&r1[(i * 256 + t) * 8] = z;
    }
}

// ---------------------------------------------------------------- kernel 1
// One block per (b,h): NCHW fp32 -> padded NHWC bf16 row transpose + pooling
// partial sums (computed from the LDS tile; no shuffles).
// LDS tile: u16 [64 w][32 slots of 8c], physical slot = s ^ (w>>2).
__global__ __launch_bounds__(256) void transpose_pool_k(const float* __restrict__ x,
                                                        u16* __restrict__ xpadT,
                                                        float* __restrict__ pooled) {
    __shared__ u16 tile[64 * 256];          // 32 KB
    int b = blockIdx.x / 56;
    int h = blockIdx.x % 56;
    int t = threadIdx.x;

    // ---- write phase: coalesced float4 reads along w
    int w4 = t & 15, c_sub = t >> 4;        // w4: 0..13 valid (56 w), c_sub: 0..15
    if (w4 < 14) {
        const float* xp = x + ((size_t)b * NC + c_sub) * NP + (size_t)h * NW + w4 * 4;
        #pragma unroll
        for (int it = 0; it < 16; ++it) {
            int c = it * 16 + c_sub;
            f32x4 v = *(const f32x4*)(xp + (size_t)it * 16 * NP);
            int key = w4;                    // (w>>2) for all 4 written rows
            int base = ((c >> 3) ^ key) * 8 + (c & 7);
            #pragma unroll
            for (int i = 0; i < 4; ++i)
                tile[(w4 * 4 + i) * 256 + base] = f2bf(v[i]);
        }
    }
    __syncthreads();

    // ---- global write phase: u16x8 along c, 1 KB/wave
    {
        int c8 = t & 31, whi = t >> 5;       // whi: 0..7
        u16* orow = xpadT + ((size_t)(b * HP + h + 1)) * WP * NC;
        #pragma unroll
        for (int j = 0; j < 8; ++j) {
            int wp = whi * 8 + j;
            u16x8 v = {0, 0, 0, 0, 0, 0, 0, 0};
            if (wp >= 1 && wp <= 56) {
                int w = wp - 1;
                v = *(const u16x8*)&tile[w * 256 + ((c8 ^ (w >> 2)) * 8)];
            }
            *(u16x8*)&orow[wp * NC + c8 * 8] = v;
        }
    }

    // ---- pool phase: per-thread channel sum over the 56 w of this row
    {
        int c = t;
        int s = c >> 3, sub = c & 7;
        float sum = 0.0f;
        #pragma unroll
        for (int w = 0; w < 56; ++w) {
            u16 u = tile[w * 256 + ((s ^ (w >> 2)) * 8) + sub];
            sum += __uint_as_float(((unsigned)u) << 16);
        }
        atomicAdd(&pooled[b * 256 + c], sum);
    }
}

// ---------------------------------------------------------------- kernel 2
// routing: rt = (pooled/3136) @ proj_w^T + proj_b ; sigmoid ; avgpool(8) -> r[32][8]
__global__ __launch_bounds__(64) void routing(const float* __restrict__ pooled,
                                              const float* __restrict__ proj_w,
                                              const float* __restrict__ proj_b,
                                              float* __restrict__ r) {
    __shared__ float ps[256];
    __shared__ float sg[64];
    int b = blockIdx.x, j = threadIdx.x;
    for (int i = j; i < 256; i += 64) ps[i] = pooled[b * NC + i] * (1.0f / 3136.0f);
    __syncthreads();
    float acc = proj_b[j];
    for (int c = 0; c < 256; ++c) acc += ps[c] * proj_w[j * NC + c];
    sg[j] = 1.0f / (1.0f + expf(-acc));
    __syncthreads();
    if (j < NE) {
        float s = 0.0f;
        #pragma unroll
        for (int q = 0; q < 8; ++q) s += sg[j * 8 + q];
        r[b * NE + j] = s * 0.125f;
    }
}

// ---------------------------------------------------------------- kernel 3
// wmix[b][kk][o][c] = bf16( sum_e r[b][e] * expert_w[e][o][c][kk] )
__global__ __launch_bounds__(256) void mix_w(const float* __restrict__ expert_w,
                                             const float* __restrict__ r,
                                             u16* __restrict__ wmix) {
    __shared__ float lr[256];
    int o = blockIdx.x, c = threadIdx.x;
    lr[c] = r[c];                               // 32*8 = 256
    __syncthreads();
    float w[8][9];
    #pragma unroll
    for (int e = 0; e < 8; ++e) {
        const float* p = expert_w + ((size_t)((e * NO + o) * NC + c)) * 9;
        #pragma unroll
        for (int kk = 0; kk < 9; ++kk) w[e][kk] = p[kk];
    }
    for (int b = 0; b < NB; ++b) {
        float acc[9] = {0, 0, 0, 0, 0, 0, 0, 0, 0};
        #pragma unroll
        for (int e = 0; e < 8; ++e) {
            float rv = lr[b * 8 + e];
            #pragma unroll
            for (int kk = 0; kk < 9; ++kk) acc[kk] += rv * w[e][kk];
        }
        #pragma unroll
        for (int kk = 0; kk < 9; ++kk)
            wmix[((size_t)((b * 9 + kk) * NO + o)) * NC + c] = f2bf(acc[kk]);
    }
}

// ---------------------------------------------------------------- kernel 4
// Implicit-GEMM conv. 256 threads (4 waves). Per block: b, FULL o=256,
// p-tile 112. Wave w owns o-rows [w*64, w*64+64): acc[4][7], B-frag
// reused across 4 mi (LDS reads: 14 per 56 MFMAs).
// A (weights): DIRECT global->VGPR, double-buffered (abuf0/abuf1), issued
//   one tap ahead with sched_barrier(0) pinning the issue slot and counted
//   s_waitcnt vmcnt(8) before each tap (16 loads in flight steady-state,
//   never drained to 0 mid-loop -- T4). Buffer parity alternates per
//   c0-chunk (9 taps odd) so the cross-chunk prefetch stays uniform.
// B (image): 4 padded rows [256x64] staged once per c0 via global_load_lds,
//   XOR-swizzled via pre-swizzled global source (2 barriers per c0).
// Grid 896 = 8 XCD x 112, bijective swizzle: each XCD owns 4 consecutive b.
__global__ __launch_bounds__(256, 2) void conv_k(const u16* __restrict__ wmix,
                                                 const u16* __restrict__ xpadT,
                                                 float* __restrict__ out) {
    __shared__ u16 Bs[256 * 64];       // 32 KB (the only LDS)
    char* Bsc = (char*)Bs;

    int tid  = threadIdx.x;
    int lane = tid & 63, wid = tid >> 6;     // wid 0..3
    int ln = lane & 15, hi = lane >> 4;

    int bid = blockIdx.x;
    int logical = (bid & 7) * 112 + (bid >> 3);
    int b  = logical / 28;
    int nt = logical % 28;
    int h0 = nt * 2;          // padded image row base
    int p0 = nt * 112;

    const u16* apane = wmix + (size_t)b * 9 * 65536;                 // + kk*65536 + o*256 + c
    const u16* xbase = xpadT + ((size_t)(b * HP + h0)) * WP * NC;    // + rw*256 + c

    // per-lane A base: row = wid*64 + ln, k-slice offset hi*8 elements
    const u16* alane = apane + (size_t)(wid * 64 + ln) * 256 + hi * 8;

    // ---- B staging: thread t covers rows t3+i*32, slot t7 (pre-swizzled src)
    int t3 = tid >> 3, t7 = tid & 7;
    int bstg_src = t3 * 256 + ((t7 ^ (t3 & 7)) * 8);   // elements
    int bstg_dst = tid * 16;                            // bytes, linear
    #define STAGE_B(C0) {                                                   \
        _Pragma("unroll")                                                   \
        for (int i = 0; i < 8; ++i)                                         \
            gl_lds16(xbase + (C0) + bstg_src + i * 8192,                    \
                     Bsc + bstg_dst + i * 4096);                            \
    }

    // A fragment registers: [mi*2+ks], two named buffers (no dynamic index)
    bf16x8 abuf0[8], abuf1[8];
    #define ISSUE_A(KK, C0, ABUF) {                                         \
        const u16* ap_ = alane + (KK) * 65536 + (C0);                       \
        _Pragma("unroll")                                                   \
        for (int mi = 0; mi < 4; ++mi) {                                    \
            ABUF[mi * 2 + 0] = *(const bf16x8*)(ap_ + mi * 4096);           \
            ABUF[mi * 2 + 1] = *(const bf16x8*)(ap_ + mi * 4096 + 32);      \
        }                                                                   \
    }

    // accumulators: 4 mi x 7 ni
    f32x4 acc[4][7];
    #pragma unroll
    for (int mi = 0; mi < 4; ++mi)
        #pragma unroll
        for (int ni = 0; ni < 7; ++ni) acc[mi][ni] = (f32x4){0.f, 0.f, 0.f, 0.f};

    // per-lane B row bases: p = ni*16 + ln ; rw = hr*64 + wv + 1
    int rwbase[7];
    #pragma unroll
    for (int ni = 0; ni < 7; ++ni) {
        int p  = ni * 16 + ln;
        int hr = (p >= 56) ? 1 : 0;
        int wv = p - hr * 56;
        rwbase[ni] = hr * 64 + wv + 1;
    }

    #define TAP_COMPUTE(KK, ABUF) {                                         \
        const int dh = (KK) / 3, kw = (KK) % 3;                             \
        _Pragma("unroll")                                                   \
        for (int ks = 0; ks < 2; ++ks) {                                    \
            _Pragma("unroll")                                               \
            for (int ni = 0; ni < 7; ++ni) {                                \
                int rw   = rwbase[ni] + dh * 64 + kw - 1;                   \
                int boff = rw * 128 + ((((ks << 2) + hi) ^ (rw & 7)) << 4); \
                bf16x8 bv = *(const bf16x8*)(Bsc + boff);                   \
                acc[0][ni] = __builtin_amdgcn_mfma_f32_16x16x32_bf16(ABUF[0 * 2 + ks], bv, acc[0][ni], 0, 0, 0); \
                acc[1][ni] = __builtin_amdgcn_mfma_f32_16x16x32_bf16(ABUF[1 * 2 + ks], bv, acc[1][ni], 0, 0, 0); \
                acc[2][ni] = __builtin_amdgcn_mfma_f32_16x16x32_bf16(ABUF[2 * 2 + ks], bv, acc[2][ni], 0, 0, 0); \
                acc[3][ni] = __builtin_amdgcn_mfma_f32_16x16x32_bf16(ABUF[3 * 2 + ks], bv, acc[3][ni], 0, 0, 0); \
            }                                                               \
        }                                                                   \
    }

    // One c0 chunk; BA = buffer of even taps, BB = odd taps. The cross-chunk
    // prefetch ISSUE_A(0, C0+64) targets BB == next chunk's BA (9 odd).
    #define CHUNK(C0, BA, BB, LAST) {                                       \
        ISSUE_A(1, C0, BB) SBAR() VM_WAIT(8) TAP_COMPUTE(0, BA)             \
        ISSUE_A(2, C0, BA) SBAR() VM_WAIT(8) TAP_COMPUTE(1, BB)             \
        ISSUE_A(3, C0, BB) SBAR() VM_WAIT(8) TAP_COMPUTE(2, BA)             \
        ISSUE_A(4, C0, BA) SBAR() VM_WAIT(8) TAP_COMPUTE(3, BB)             \
        ISSUE_A(5, C0, BB) SBAR() VM_WAIT(8) TAP_COMPUTE(4, BA)             \
        ISSUE_A(6, C0, BA) SBAR() VM_WAIT(8) TAP_COMPUTE(5, BB)             \
        ISSUE_A(7, C0, BB) SBAR() VM_WAIT(8) TAP_COMPUTE(6, BA)             \
        ISSUE_A(8, C0, BA) SBAR() VM_WAIT(8) TAP_COMPUTE(7, BB)             \
        if (LAST) { VM_WAIT(0) TAP_COMPUTE(8, BA) }                         \
        else {                                                              \
            ISSUE_A(0, (C0) + 64, BB) SBAR() VM_WAIT(8) TAP_COMPUTE(8, BA)  \
            __syncthreads();                                                \
            STAGE_B((C0) + 64)                                              \
            __syncthreads();                                                \
        }                                                                   \
    }

    // prologue: B(c0=0) staged, A(tap0) in flight -> drained by the barrier
    STAGE_B(0)
    ISSUE_A(0, 0, abuf0)
    __syncthreads();

    CHUNK(0,   abuf0, abuf1, 0)
    CHUNK(64,  abuf1, abuf0, 0)
    CHUNK(128, abuf0, abuf1, 0)
    CHUNK(192, abuf1, abuf0, 1)

    #undef CHUNK
    #undef TAP_COMPUTE
    #undef ISSUE_A
    #undef STAGE_B

    // epilogue: D col = lane&15 (p), row = (lane>>4)*4 + reg (o)
    float* op = out + ((size_t)(b * NO + wid * 64)) * NP + p0;
    #pragma unroll
    for (int mi = 0; mi < 4; ++mi)
        #pragma unroll
        for (int ni = 0; ni < 7; ++ni) {
            f32x4 v = acc[mi][ni];
            int col = ni * 16 + ln;
            #pragma unroll
            for (int rg = 0; rg < 4; ++rg) {
                int row = mi * 16 + hi * 4 + rg;
                op[(size_t)row * NP + col] = v[rg];
            }
        }
}

// ---------------------------------------------------------------- launch
extern "C" void kernel_launch(void* const* d_in, const int* in_sizes, int n_in,
                              void* d_out, int out_size, void* d_ws, size_t ws_size,
                              hipStream_t stream) {
    (void)in_sizes; (void)n_in; (void)out_size; (void)ws_size;
    const float* x        = (const float*)d_in[0];
    const float* proj_w   = (const float*)d_in[1];
    const float* proj_b   = (const float*)d_in[2];
    const float* expert_w = (const float*)d_in[3];
    float* out = (float*)d_out;
    char*  ws  = (char*)d_ws;

    u16*   wmix   = (u16*)(ws + WMIX_OFF);
    u16*   xpadT  = (u16*)(ws + XPT_OFF);
    float* pooled = (float*)(ws + POOL_OFF);
    float* rbuf   = (float*)(ws + RBUF_OFF);

    zero_k<<<dim3(32), dim3(256), 0, stream>>>(pooled, xpadT);
    transpose_pool_k<<<dim3(32 * 56), dim3(256), 0, stream>>>(x, xpadT, pooled);
    routing<<<dim3(32), dim3(64), 0, stream>>>(pooled, proj_w, proj_b, rbuf);
    mix_w<<<dim3(256), dim3(256), 0, stream>>>(expert_w, rbuf, wmix);
    conv_k<<<dim3(32 * 28), dim3(256), 0, stream>>>(wmix, xpadT, out);
}

// Round 11
// 220.714 us; speedup vs baseline: 1.3309x; 1.3309x over previous
//
#include <hip/hip_runtime.h>
#include <math.h>

typedef unsigned short u16;
typedef __attribute__((ext_vector_type(8))) short    bf16x8;
typedef __attribute__((ext_vector_type(8))) unsigned short u16x8;
typedef __attribute__((ext_vector_type(4))) float    f32x4;

// Problem constants
#define NB   32        // batch
#define NC   256       // in channels
#define NO   256       // out channels
#define NH   56
#define NW   56
#define NP   3136      // H*W
#define NE   8
#define NID  64
#define HP   58        // padded rows
#define WP   64        // padded row width (aligned)

// Workspace layout (bytes)
#define WMIX_OFF   0                    // u16 [32][9][256][256] = 37,748,736 B
#define XPT_OFF    37748736             // u16 [32][58][64][256] = 60,817,408 B
#define POOL_OFF   98566144             // f32 [32][256]
#define RBUF_OFF   98598912             // f32 [32][8]

__device__ __forceinline__ u16 f2bf(float f) {
    unsigned u = __float_as_uint(f);
    unsigned r = (u + 0x7FFFu + ((u >> 16) & 1u)) >> 16;   // RNE
    return (u16)r;
}

__device__ __forceinline__ void gl_lds16(const void* g, void* l) {
    __builtin_amdgcn_global_load_lds(
        (const __attribute__((address_space(1))) unsigned int*)g,
        (__attribute__((address_space(3))) unsigned int*)l, 16, 0, 0);
}

#define SBAR() __builtin_amdgcn_sched_barrier(0);
// counted wait (perf hint only; correctness is register-dep guaranteed)
#define VM_WAIT(N) { asm volatile("s_waitcnt vmcnt(" #N ")" ::: "memory"); \
                     __builtin_amdgcn_sched_barrier(0); }

// ---------------------------------------------------------------- kernel 0
// Zero pooled accumulators + the two border rows (h'=0,57) of xpadT.
__global__ __launch_bounds__(256) void zero_k(float* __restrict__ pooled,
                                              u16* __restrict__ xpadT) {
    int b = blockIdx.x, t = threadIdx.x;
    pooled[b * 256 + t] = 0.0f;
    u16x8 z = {0, 0, 0, 0, 0, 0, 0, 0};
    u16* r0 = xpadT + ((size_t)(b * HP + 0)) * WP * NC;
    u16* r1 = xpadT + ((size_t)(b * HP + 57)) * WP * NC;
    #pragma unroll
    for (int i = 0; i < 8; ++i) {
        *(u16x8*)&r0[(i * 256 + t) * 8] = z;
        *(u16x8*)&r1[(i * 256 + t) * 8] = z;
    }
}

// ---------------------------------------------------------------- kernel 1
// One block per (b,h): NCHW fp32 -> padded NHWC bf16 row transpose + pooling
// partial sums (computed from the LDS tile; no shuffles).
// LDS tile: u16 [64 w][32 slots of 8c], physical slot = s ^ (w>>2).
__global__ __launch_bounds__(256) void transpose_pool_k(const float* __restrict__ x,
                                                        u16* __restrict__ xpadT,
                                                        float* __restrict__ pooled) {
    __shared__ u16 tile[64 * 256];          // 32 KB
    int b = blockIdx.x / 56;
    int h = blockIdx.x % 56;
    int t = threadIdx.x;

    // ---- write phase: coalesced float4 reads along w
    int w4 = t & 15, c_sub = t >> 4;        // w4: 0..13 valid (56 w), c_sub: 0..15
    if (w4 < 14) {
        const float* xp = x + ((size_t)b * NC + c_sub) * NP + (size_t)h * NW + w4 * 4;
        #pragma unroll
        for (int it = 0; it < 16; ++it) {
            int c = it * 16 + c_sub;
            f32x4 v = *(const f32x4*)(xp + (size_t)it * 16 * NP);
            int key = w4;                    // (w>>2) for all 4 written rows
            int base = ((c >> 3) ^ key) * 8 + (c & 7);
            #pragma unroll
            for (int i = 0; i < 4; ++i)
                tile[(w4 * 4 + i) * 256 + base] = f2bf(v[i]);
        }
    }
    __syncthreads();

    // ---- global write phase: u16x8 along c, 1 KB/wave
    {
        int c8 = t & 31, whi = t >> 5;       // whi: 0..7
        u16* orow = xpadT + ((size_t)(b * HP + h + 1)) * WP * NC;
        #pragma unroll
        for (int j = 0; j < 8; ++j) {
            int wp = whi * 8 + j;
            u16x8 v = {0, 0, 0, 0, 0, 0, 0, 0};
            if (wp >= 1 && wp <= 56) {
                int w = wp - 1;
                v = *(const u16x8*)&tile[w * 256 + ((c8 ^ (w >> 2)) * 8)];
            }
            *(u16x8*)&orow[wp * NC + c8 * 8] = v;
        }
    }

    // ---- pool phase: per-thread channel sum over the 56 w of this row
    {
        int c = t;
        int s = c >> 3, sub = c & 7;
        float sum = 0.0f;
        #pragma unroll
        for (int w = 0; w < 56; ++w) {
            u16 u = tile[w * 256 + ((s ^ (w >> 2)) * 8) + sub];
            sum += __uint_as_float(((unsigned)u) << 16);
        }
        atomicAdd(&pooled[b * 256 + c], sum);
    }
}

// ---------------------------------------------------------------- kernel 2
// routing: rt = (pooled/3136) @ proj_w^T + proj_b ; sigmoid ; avgpool(8) -> r[32][8]
__global__ __launch_bounds__(64) void routing(const float* __restrict__ pooled,
                                              const float* __restrict__ proj_w,
                                              const float* __restrict__ proj_b,
                                              float* __restrict__ r) {
    __shared__ float ps[256];
    __shared__ float sg[64];
    int b = blockIdx.x, j = threadIdx.x;
    for (int i = j; i < 256; i += 64) ps[i] = pooled[b * NC + i] * (1.0f / 3136.0f);
    __syncthreads();
    float acc = proj_b[j];
    for (int c = 0; c < 256; ++c) acc += ps[c] * proj_w[j * NC + c];
    sg[j] = 1.0f / (1.0f + expf(-acc));
    __syncthreads();
    if (j < NE) {
        float s = 0.0f;
        #pragma unroll
        for (int q = 0; q < 8; ++q) s += sg[j * 8 + q];
        r[b * NE + j] = s * 0.125f;
    }
}

// ---------------------------------------------------------------- kernel 3
// wmix[b][kk][o][c] = bf16( sum_e r[b][e] * expert_w[e][o][c][kk] )
__global__ __launch_bounds__(256) void mix_w(const float* __restrict__ expert_w,
                                             const float* __restrict__ r,
                                             u16* __restrict__ wmix) {
    __shared__ float lr[256];
    int o = blockIdx.x, c = threadIdx.x;
    lr[c] = r[c];                               // 32*8 = 256
    __syncthreads();
    float w[8][9];
    #pragma unroll
    for (int e = 0; e < 8; ++e) {
        const float* p = expert_w + ((size_t)((e * NO + o) * NC + c)) * 9;
        #pragma unroll
        for (int kk = 0; kk < 9; ++kk) w[e][kk] = p[kk];
    }
    for (int b = 0; b < NB; ++b) {
        float acc[9] = {0, 0, 0, 0, 0, 0, 0, 0, 0};
        #pragma unroll
        for (int e = 0; e < 8; ++e) {
            float rv = lr[b * 8 + e];
            #pragma unroll
            for (int kk = 0; kk < 9; ++kk) acc[kk] += rv * w[e][kk];
        }
        #pragma unroll
        for (int kk = 0; kk < 9; ++kk)
            wmix[((size_t)((b * 9 + kk) * NO + o)) * NC + c] = f2bf(acc[kk]);
    }
}

// ---------------------------------------------------------------- kernel 4
// Implicit-GEMM conv. 256 threads (4 waves). Per block: b, FULL o=256,
// p-tile 112. Wave w owns o-rows [w*64, w*64+64): acc[4][7], B-frag
// reused across 4 mi (LDS reads: 14 per 56 MFMAs).
// A (weights): DIRECT global->VGPR, double-buffered (abuf0/abuf1), issued
//   one tap ahead with sched_barrier(0) pinning the issue slot and counted
//   s_waitcnt vmcnt(8) before each tap (16 loads in flight steady-state,
//   never drained to 0 mid-loop -- T4). Buffer parity alternates per
//   c0-chunk (9 taps odd) so the cross-chunk prefetch stays uniform.
// __launch_bounds__(256, 1): hipcc's VGPR cap is 256/arg2 (measured across
//   r5-r10); arg2=2 capped at 128 and spilled ~105 MB. arg2=1 -> 512 cap;
//   actual use ~220 -> HW still resides 2 waves/SIMD, now spill-free.
// B (image): 4 padded rows [256x64] staged once per c0 via global_load_lds,
//   XOR-swizzled via pre-swizzled global source (2 barriers per c0).
// Grid 896 = 8 XCD x 112, bijective swizzle: each XCD owns 4 consecutive b.
__global__ __launch_bounds__(256, 1) void conv_k(const u16* __restrict__ wmix,
                                                 const u16* __restrict__ xpadT,
                                                 float* __restrict__ out) {
    __shared__ u16 Bs[256 * 64];       // 32 KB (the only LDS)
    char* Bsc = (char*)Bs;

    int tid  = threadIdx.x;
    int lane = tid & 63, wid = tid >> 6;     // wid 0..3
    int ln = lane & 15, hi = lane >> 4;

    int bid = blockIdx.x;
    int logical = (bid & 7) * 112 + (bid >> 3);
    int b  = logical / 28;
    int nt = logical % 28;
    int h0 = nt * 2;          // padded image row base
    int p0 = nt * 112;

    const u16* apane = wmix + (size_t)b * 9 * 65536;                 // + kk*65536 + o*256 + c
    const u16* xbase = xpadT + ((size_t)(b * HP + h0)) * WP * NC;    // + rw*256 + c

    // per-lane A base: row = wid*64 + ln, k-slice offset hi*8 elements
    const u16* alane = apane + (size_t)(wid * 64 + ln) * 256 + hi * 8;

    // ---- B staging: thread t covers rows t3+i*32, slot t7 (pre-swizzled src)
    int t3 = tid >> 3, t7 = tid & 7;
    int bstg_src = t3 * 256 + ((t7 ^ (t3 & 7)) * 8);   // elements
    int bstg_dst = tid * 16;                            // bytes, linear
    #define STAGE_B(C0) {                                                   \
        _Pragma("unroll")                                                   \
        for (int i = 0; i < 8; ++i)                                         \
            gl_lds16(xbase + (C0) + bstg_src + i * 8192,                    \
                     Bsc + bstg_dst + i * 4096);                            \
    }

    // A fragment registers: [mi*2+ks], two named buffers (no dynamic index)
    bf16x8 abuf0[8], abuf1[8];
    #define ISSUE_A(KK, C0, ABUF) {                                         \
        const u16* ap_ = alane + (KK) * 65536 + (C0);                       \
        _Pragma("unroll")                                                   \
        for (int mi = 0; mi < 4; ++mi) {                                    \
            ABUF[mi * 2 + 0] = *(const bf16x8*)(ap_ + mi * 4096);           \
            ABUF[mi * 2 + 1] = *(const bf16x8*)(ap_ + mi * 4096 + 32);      \
        }                                                                   \
    }

    // accumulators: 4 mi x 7 ni
    f32x4 acc[4][7];
    #pragma unroll
    for (int mi = 0; mi < 4; ++mi)
        #pragma unroll
        for (int ni = 0; ni < 7; ++ni) acc[mi][ni] = (f32x4){0.f, 0.f, 0.f, 0.f};

    // per-lane B row bases: p = ni*16 + ln ; rw = hr*64 + wv + 1
    int rwbase[7];
    #pragma unroll
    for (int ni = 0; ni < 7; ++ni) {
        int p  = ni * 16 + ln;
        int hr = (p >= 56) ? 1 : 0;
        int wv = p - hr * 56;
        rwbase[ni] = hr * 64 + wv + 1;
    }

    #define TAP_COMPUTE(KK, ABUF) {                                         \
        const int dh = (KK) / 3, kw = (KK) % 3;                             \
        _Pragma("unroll")                                                   \
        for (int ks = 0; ks < 2; ++ks) {                                    \
            _Pragma("unroll")                                               \
            for (int ni = 0; ni < 7; ++ni) {                                \
                int rw   = rwbase[ni] + dh * 64 + kw - 1;                   \
                int boff = rw * 128 + ((((ks << 2) + hi) ^ (rw & 7)) << 4); \
                bf16x8 bv = *(const bf16x8*)(Bsc + boff);                   \
                acc[0][ni] = __builtin_amdgcn_mfma_f32_16x16x32_bf16(ABUF[0 * 2 + ks], bv, acc[0][ni], 0, 0, 0); \
                acc[1][ni] = __builtin_amdgcn_mfma_f32_16x16x32_bf16(ABUF[1 * 2 + ks], bv, acc[1][ni], 0, 0, 0); \
                acc[2][ni] = __builtin_amdgcn_mfma_f32_16x16x32_bf16(ABUF[2 * 2 + ks], bv, acc[2][ni], 0, 0, 0); \
                acc[3][ni] = __builtin_amdgcn_mfma_f32_16x16x32_bf16(ABUF[3 * 2 + ks], bv, acc[3][ni], 0, 0, 0); \
            }                                                               \
        }                                                                   \
    }

    // One c0 chunk; BA = buffer of even taps, BB = odd taps. The cross-chunk
    // prefetch ISSUE_A(0, C0+64) targets BB == next chunk's BA (9 odd).
    #define CHUNK(C0, BA, BB, LAST) {                                       \
        ISSUE_A(1, C0, BB) SBAR() VM_WAIT(8) TAP_COMPUTE(0, BA)             \
        ISSUE_A(2, C0, BA) SBAR() VM_WAIT(8) TAP_COMPUTE(1, BB)             \
        ISSUE_A(3, C0, BB) SBAR() VM_WAIT(8) TAP_COMPUTE(2, BA)             \
        ISSUE_A(4, C0, BA) SBAR() VM_WAIT(8) TAP_COMPUTE(3, BB)             \
        ISSUE_A(5, C0, BB) SBAR() VM_WAIT(8) TAP_COMPUTE(4, BA)             \
        ISSUE_A(6, C0, BA) SBAR() VM_WAIT(8) TAP_COMPUTE(5, BB)             \
        ISSUE_A(7, C0, BB) SBAR() VM_WAIT(8) TAP_COMPUTE(6, BA)             \
        ISSUE_A(8, C0, BA) SBAR() VM_WAIT(8) TAP_COMPUTE(7, BB)             \
        if (LAST) { VM_WAIT(0) TAP_COMPUTE(8, BA) }                         \
        else {                                                              \
            ISSUE_A(0, (C0) + 64, BB) SBAR() VM_WAIT(8) TAP_COMPUTE(8, BA)  \
            __syncthreads();                                                \
            STAGE_B((C0) + 64)                                              \
            __syncthreads();                                                \
        }                                                                   \
    }

    // prologue: B(c0=0) staged, A(tap0) in flight -> drained by the barrier
    STAGE_B(0)
    ISSUE_A(0, 0, abuf0)
    __syncthreads();

    CHUNK(0,   abuf0, abuf1, 0)
    CHUNK(64,  abuf1, abuf0, 0)
    CHUNK(128, abuf0, abuf1, 0)
    CHUNK(192, abuf1, abuf0, 1)

    #undef CHUNK
    #undef TAP_COMPUTE
    #undef ISSUE_A
    #undef STAGE_B

    // epilogue: D col = lane&15 (p), row = (lane>>4)*4 + reg (o)
    float* op = out + ((size_t)(b * NO + wid * 64)) * NP + p0;
    #pragma unroll
    for (int mi = 0; mi < 4; ++mi)
        #pragma unroll
        for (int ni = 0; ni < 7; ++ni) {
            f32x4 v = acc[mi][ni];
            int col = ni * 16 + ln;
            #pragma unroll
            for (int rg = 0; rg < 4; ++rg) {
                int row = mi * 16 + hi * 4 + rg;
                op[(size_t)row * NP + col] = v[rg];
            }
        }
}

// ---------------------------------------------------------------- launch
extern "C" void kernel_launch(void* const* d_in, const int* in_sizes, int n_in,
                              void* d_out, int out_size, void* d_ws, size_t ws_size,
                              hipStream_t stream) {
    (void)in_sizes; (void)n_in; (void)out_size; (void)ws_size;
    const float* x        = (const float*)d_in[0];
    const float* proj_w   = (const float*)d_in[1];
    const float* proj_b   = (const float*)d_in[2];
    const float* expert_w = (const float*)d_in[3];
    float* out = (float*)d_out;
    char*  ws  = (char*)d_ws;

    u16*   wmix   = (u16*)(ws + WMIX_OFF);
    u16*   xpadT  = (u16*)(ws + XPT_OFF);
    float* pooled = (float*)(ws + POOL_OFF);
    float* rbuf   = (float*)(ws + RBUF_OFF);

    zero_k<<<dim3(32), dim3(256), 0, stream>>>(pooled, xpadT);
    transpose_pool_k<<<dim3(32 * 56), dim3(256), 0, stream>>>(x, xpadT, pooled);
    routing<<<dim3(32), dim3(64), 0, stream>>>(pooled, proj_w, proj_b, rbuf);
    mix_w<<<dim3(256), dim3(256), 0, stream>>>(expert_w, rbuf, wmix);
    conv_k<<<dim3(32 * 28), dim3(256), 0, stream>>>(wmix, xpadT, out);
}